// Round 4
// baseline (7683536.719 us; speedup 1.0000x reference)
//
#include <hip/hip_runtime.h>

typedef unsigned long long u64;
typedef unsigned int u32;
typedef __attribute__((ext_vector_type(8))) short short8;   // bf16x8 MFMA frag
typedef __attribute__((ext_vector_type(4))) float floatx4;  // f32x4 MFMA acc

// Problem constants
#define Bc   64
#define Sc   512
#define Dc   256
#define Hc   512
#define OUTc 128

// 256 WGs x 512 thr, 142KB LDS -> 1 WG/CU.  Roles are a pure function of
// blockIdx: group = wg&7 (0-3 = L0 bg, 4-7 = L1 bg), rg = wg>>3 in [0,32).
// Under round-robin placement group == XCD, so each group's recurrent h
// exchange is XCD-local (sc0 = L2 coherence point).  Cross-layer feed h1b
// stays on the proven round-0 sc1/MALL path with 2-3 steps of pipeline slack.
// A leader-published placement vote selects sc0 vs sc1 for intra-group ops;
// fallback is always-correct sc1.  All spins tightly bounded: a protocol bug
// yields a fast wrong-output failure, never a hang.
#define NWG  256
#define NTHR 512
#define JPW  16     // j indices per WG
#define NRW  64     // weight rows per WG (4 gates x 16 j)
#define KPB  1032   // bf16 LDS row stride (max K 1024 + 8)
#define HQ   8192   // u64s per h1b slot: [128 k4][64 b]
#define SPIN1 (1 << 17)   // per-step poll bound (safety valve only)
#define SPIN2 (1 << 22)   // one-time poll bound

// workspace layout (memset to 0 each launch)
#define XARR_OFF 0              // u32[256]  xcd-id+1 per WG
#define XDEC_OFF 1024           // u32[8]    leader vote: 0 pend, 1 sc1, 2 sc0
#define F0L_OFF  1152           // u32[4][32] L0 local flags (s+1: h1 local-visible)
#define F1L_OFF  1664           // u32[4][32] L1 local flags (s+1: h2 local-visible)
#define F0R_OFF  2176           // u32[4][32] L0 feed flags (s: h1b[s-1] MALL-visible)
#define F1R_OFF  2688           // u32[4][32] L1 WAR flags (s+1: consumed h1b[s])
#define H1L_OFF  4096                         // u64[4 bg][2 slot][128 k4][16 b]
#define H2L_OFF  (4096 + 131072)              // u64[4 bg][2 slot][128 k4][16 b]
#define H1B_OFF  (4096 + 262144)              // u64[3 slot][128 k4][64 b]  (sc1 feed)
#define WS_BYTES (4096 + 262144 + 3 * 65536)

__device__ __forceinline__ short bf16_rne(float f) {
    u32 u = __float_as_uint(f);
    u += 0x7fffu + ((u >> 16) & 1u);
    return (short)(u >> 16);
}
__device__ __forceinline__ float4 unpack4(u64 v) {
    u32 lo = (u32)v, hi = (u32)(v >> 32);
    float4 f;
    f.x = __uint_as_float(lo << 16);
    f.y = __uint_as_float(lo & 0xffff0000u);
    f.z = __uint_as_float(hi << 16);
    f.w = __uint_as_float(hi & 0xffff0000u);
    return f;
}
__device__ __forceinline__ u32 pack2_rne(float a, float b) {
    u32 ua = __float_as_uint(a), ub = __float_as_uint(b);
    ua += 0x7fffu + ((ua >> 16) & 1u);
    ub += 0x7fffu + ((ub >> 16) & 1u);
    return (ua >> 16) | (ub & 0xffff0000u);
}
__device__ __forceinline__ short8 frag2(u64 a, u64 b) {
    union { u64 u[2]; short8 s; } c; c.u[0] = a; c.u[1] = b; return c.s;
}
__device__ __forceinline__ float sigmoidf_fast(float v) {
    return 1.0f / (1.0f + __expf(-v));
}
__device__ __forceinline__ float tanhf_fast(float v) {
    return 2.0f / (1.0f + __expf(-2.0f * v)) - 1.0f;
}

// ---- scope helpers: sc0 = XCD-L2 coherence point, sc1 = device/MALL ----
__device__ __forceinline__ void ld64_sc0(u64& d, const u64* p) {
    asm volatile("global_load_dwordx2 %0, %1, off sc0" : "=v"(d) : "v"(p) : "memory");
}
__device__ __forceinline__ void ld64_sc1(u64& d, const u64* p) {
    asm volatile("global_load_dwordx2 %0, %1, off sc1" : "=v"(d) : "v"(p) : "memory");
}
__device__ __forceinline__ u64 ld64_sync(const u64* p, bool loc) {
    u64 v;
    if (loc) asm volatile("global_load_dwordx2 %0, %1, off sc0\n\ts_waitcnt vmcnt(0)"
                          : "=v"(v) : "v"(p) : "memory");
    else     asm volatile("global_load_dwordx2 %0, %1, off sc1\n\ts_waitcnt vmcnt(0)"
                          : "=v"(v) : "v"(p) : "memory");
    return v;
}
__device__ __forceinline__ u32 ldf_sc0(const u32* p) {
    u32 v;
    asm volatile("global_load_dword %0, %1, off sc0\n\ts_waitcnt vmcnt(0)"
                 : "=v"(v) : "v"(p) : "memory");
    return v;
}
__device__ __forceinline__ u32 ldf_sc1(const u32* p) {
    u32 v;
    asm volatile("global_load_dword %0, %1, off sc1\n\ts_waitcnt vmcnt(0)"
                 : "=v"(v) : "v"(p) : "memory");
    return v;
}
__device__ __forceinline__ u32 ldf_loc(const u32* p, bool loc) {
    return loc ? ldf_sc0(p) : ldf_sc1(p);
}
__device__ __forceinline__ void st32_sc0(u32* p, u32 v) {
    asm volatile("global_store_dword %0, %1, off sc0" :: "v"(p), "v"(v) : "memory");
}
__device__ __forceinline__ void st32_sc1(u32* p, u32 v) {
    asm volatile("global_store_dword %0, %1, off sc1" :: "v"(p), "v"(v) : "memory");
}
__device__ __forceinline__ void st32_loc(u32* p, u32 v, bool loc) {
    if (loc) st32_sc0(p, v); else st32_sc1(p, v);
}
#define VMCNT(n) do { asm volatile("s_waitcnt vmcnt(" #n ")" ::: "memory"); \
                      __builtin_amdgcn_sched_barrier(0); } while (0)
#define LGKM0    do { asm volatile("s_waitcnt lgkmcnt(0)" ::: "memory"); } while (0)
__device__ __forceinline__ void bar() {   // raw s_barrier: no implicit drain
    asm volatile("s_barrier" ::: "memory");
}

#define MFMA16(A, B, C) __builtin_amdgcn_mfma_f32_16x16x32_bf16((A), (B), (C), 0, 0, 0)

extern "C" __global__ void __launch_bounds__(NTHR)
lstm_persist(const float* __restrict__ x,
             const float* __restrict__ Wih0, const float* __restrict__ Whh0,
             const float* __restrict__ bih0, const float* __restrict__ bhh0,
             const float* __restrict__ Wih1, const float* __restrict__ Whh1,
             const float* __restrict__ bih1, const float* __restrict__ bhh1,
             const float* __restrict__ fcw, const float* __restrict__ fcb,
             float* __restrict__ out, float* __restrict__ wsf)
{
    __shared__ short Wl[NRW * KPB];          // 132 KB bf16 weights, resident
    __shared__ float red[8 * 16 * 20];       // 10.2 KB C-park / FC reduce
    __shared__ int sh_loc;

    char* wsb = (char*)wsf;
    u32* xarr = (u32*)(wsb + XARR_OFF);
    u32* xdec = (u32*)(wsb + XDEC_OFF);
    u32* f0l  = (u32*)(wsb + F0L_OFF);
    u32* f1l  = (u32*)(wsb + F1L_OFF);
    u32* f0r  = (u32*)(wsb + F0R_OFF);
    u32* f1r  = (u32*)(wsb + F1R_OFF);
    u64* h1l  = (u64*)(wsb + H1L_OFF);
    u64* h2l  = (u64*)(wsb + H2L_OFF);
    u64* h1b  = (u64*)(wsb + H1B_OFF);

    const int wg  = blockIdx.x;
    const int tid = threadIdx.x;

    // publish my physical XCD id ASAP (data-as-flag: 0 -> xid+1, set once)
    if (tid == 0) {
        u32 xid;
        asm volatile("s_getreg_b32 %0, hwreg(HW_REG_XCC_ID, 0, 32)" : "=s"(xid));
        st32_sc1(xarr + wg, (xid & 7u) + 1u);
    }

    const int group = wg & 7;                // pure blockIdx role: coverage safe
    const int rg    = wg >> 3;               // 0..31
    const bool isL1 = group >= 4;
    const int bg    = group & 3;
    const int j0 = rg * JPW;
    const int K  = isL1 ? 1024 : 768;
    const int KD = isL1 ? 512  : 256;

    // ---- one-time weight staging: 64 rows (g*16+jl) x K, fp32 -> bf16 ----
    {
        const float* Wi = isL1 ? Wih1 : Wih0;
        const float* Wh = isL1 ? Whh1 : Whh0;
        for (int r = 0; r < NRW; ++r) {
            const int row = (r >> 4) * Hc + j0 + (r & 15);
            for (int c = tid; c < K; c += NTHR) {
                float v = (c < KD) ? Wi[(size_t)row * KD + c] : Wh[(size_t)row * Hc + (c - KD)];
                Wl[r * KPB + c] = bf16_rne(v);
            }
        }
    }

    const int w = tid >> 6, lane = tid & 63;

    // ---- leader-published placement vote (consistent across the group) ----
    if (rg == 0 && w == 0) {                 // leader WG: wg == group
        u32 v = 0; int it = 0;
        for (;;) {
            v = ldf_sc1(xarr + (lane & 31) * 8 + group);
            if (__all(v != 0) || ++it > SPIN2) break;
            __builtin_amdgcn_s_sleep(2);
        }
        u32 v0 = __shfl(v, 0);
        u32 dec = (__all(v != 0) && __all(v == v0)) ? 2u : 1u;
        if (lane == 0) st32_sc1(xdec + group, dec);
    }
    if (w == 0) {
        u32 d = 0; int it = 0;
        for (;;) {
            d = ldf_sc1(xdec + group);
            if (d != 0 || ++it > SPIN2) break;
            __builtin_amdgcn_s_sleep(2);
        }
        if (tid == 0) sh_loc = (d == 2u) ? 1 : 0;
    }
    __syncthreads();
    const bool loc = sh_loc != 0;

    u64* h1l_bg = h1l + (size_t)bg * 4096;   // [2 slot][128 k4][16 b]
    u64* h2l_bg = h2l + (size_t)bg * 4096;
    u32* f0l_bg = f0l + bg * 32;
    u32* f1l_bg = f1l + bg * 32;
    u32* f0r_bg = f0r + bg * 32;
    u32* f1r_bg = f1r + bg * 32;

    // MFMA wave mapping (proven): w = (gate g)*2 + K-half
    const int g = w >> 1, half = w & 1;
    const int quad = lane >> 4, c16 = lane & 15;
    const int bglob = bg * 16 + c16;
    const int wrowb = (g * 16 + c16) * KPB;

    // cell mapping: tid<128 -> (bl, jp), 2 cells (j = j0+2jp, +1)
    const int bl = tid & 15, jp = tid >> 4;
    float cst[2] = {0.0f, 0.0f};
    float bias2[2][4];
    {
        const float* bi = isL1 ? bih1 : bih0;
        const float* bh = isL1 ? bhh1 : bhh0;
#pragma unroll
        for (int jj2 = 0; jj2 < 2; ++jj2) {
            const int j = j0 + 2 * jp + jj2;
#pragma unroll
            for (int gg = 0; gg < 4; ++gg)
                bias2[jj2][gg] = bi[gg * Hc + j] + bh[gg * Hc + j];
        }
    }
    // local h slot [128 k4][16 b](u64) as u32: row k4 = 4rg + (jp>>1)
    const int hoff  = (rg * 4 + (jp >> 1)) * 32 + 2 * bl + (jp & 1);
    // global h1b slot [128 k4][64 b](u64) as u32 (round-0 proven layout)
    const int hsoff = ((j0 + 2 * jp) >> 2) * 128 + 2 * (bg * 16 + bl) + (jp & 1);

    u64 F[16], G[16];
    u32 warv = 0, feedv = 0;

    for (int s = 0; s < Sc; ++s) {
        floatx4 acc = {0.0f, 0.0f, 0.0f, 0.0f};

        // ============== P0: x-phase (L0) + polls (w0) ==========================
        if (!isL1) {
            // x-phase: dependency-free; overlaps producer stragglers (proven)
            {
                const float* xp = x + (size_t)bglob * Sc * Dc + (size_t)s * Dc
                                + half * 128 + quad * 8;
                float Xv[32];
#pragma unroll
                for (int i = 0; i < 8; ++i)
                    *(float4*)&Xv[4 * i] = *(const float4*)(xp + (i >> 1) * 32 + (i & 1) * 4);
#pragma unroll
                for (int i = 0; i < 4; ++i) {
                    short8 Bv;
#pragma unroll
                    for (int jj = 0; jj < 8; ++jj) Bv[jj] = bf16_rne(Xv[i * 8 + jj]);
                    acc = MFMA16(*(const short8*)&Wl[wrowb + half * 128 + i * 32 + quad * 8], Bv, acc);
                }
            }
            if (w == 0) {
                // peers done s-1 locally; WAR: L1 consumed h1b[s-3] (sc1, cached)
                const u32 warT = (s >= 3) ? (u32)(s - 2) : 0u;
                bool need_w = !__all(warv >= warT);
                int it = 0;
                for (;;) {
                    u32 v = ldf_loc(f0l_bg + (lane & 31), loc);
                    if (need_w) {
                        warv = ldf_sc1(f1r_bg + (lane & 31));
                        need_w = !__all(warv >= warT);
                    }
                    if ((!need_w && __all(v >= (u32)s)) || ++it > SPIN1) break;
                    __builtin_amdgcn_s_sleep(1);
                }
            }
        } else {
            if (w == 0) {
                // peers done s-1 locally; feed: h1b[s] MALL-visible (f0r >= s+1)
                const u32 ft = (u32)(s + 1);
                bool need_f = !__all(feedv >= ft);
                int it = 0;
                for (;;) {
                    u32 v = ldf_loc(f1l_bg + (lane & 31), loc);
                    if (need_f) {
                        feedv = ldf_sc1(f0r_bg + (lane & 31));
                        need_f = !__all(feedv >= ft);
                    }
                    if ((!need_f && __all(v >= (u32)s)) || ++it > SPIN1) break;
                    __builtin_amdgcn_s_sleep(1);
                }
            }
        }
        bar();   // B1: inputs for step s certified

        // ============== P1: recurrent loads + MFMA + park ======================
        if (!isL1) {
            const u64* hb = h1l_bg + (size_t)((s + 1) & 1) * 2048;   // h1[s-1] local
            if (loc) {
#pragma unroll
                for (int i = 0; i < 8; ++i) {
                    const int q8 = half * 64 + i * 8 + quad * 2;
                    ld64_sc0(F[2 * i],     hb + q8 * 16 + c16);
                    ld64_sc0(F[2 * i + 1], hb + (q8 + 1) * 16 + c16);
                }
            } else {
#pragma unroll
                for (int i = 0; i < 8; ++i) {
                    const int q8 = half * 64 + i * 8 + quad * 2;
                    ld64_sc1(F[2 * i],     hb + q8 * 16 + c16);
                    ld64_sc1(F[2 * i + 1], hb + (q8 + 1) * 16 + c16);
                }
            }
            VMCNT(0);   // F done (also retires x-loads + last step's sc1 h-store)
#pragma unroll
            for (int i = 0; i < 8; ++i)
                acc = MFMA16(*(const short8*)&Wl[wrowb + 256 + half * 256 + i * 32 + quad * 8],
                             frag2(F[2 * i], F[2 * i + 1]), acc);
        } else {
            const u64* rb = h1b + (size_t)(s % 3) * HQ;              // h1[s] feed
#pragma unroll
            for (int i = 0; i < 8; ++i) {
                const int q8 = half * 64 + i * 8 + quad * 2;
                ld64_sc1(F[2 * i],     rb + (size_t)q8 * 64 + bglob);
                ld64_sc1(F[2 * i + 1], rb + (size_t)(q8 + 1) * 64 + bglob);
            }
            const u64* gb = h2l_bg + (size_t)((s + 1) & 1) * 2048;   // h2[s-1] local
            if (loc) {
#pragma unroll
                for (int i = 0; i < 8; ++i) {
                    const int q8 = half * 64 + i * 8 + quad * 2;
                    ld64_sc0(G[2 * i],     gb + q8 * 16 + c16);
                    ld64_sc0(G[2 * i + 1], gb + (q8 + 1) * 16 + c16);
                }
            } else {
#pragma unroll
                for (int i = 0; i < 8; ++i) {
                    const int q8 = half * 64 + i * 8 + quad * 2;
                    ld64_sc1(G[2 * i],     gb + q8 * 16 + c16);
                    ld64_sc1(G[2 * i + 1], gb + (q8 + 1) * 16 + c16);
                }
            }
            VMCNT(16);   // F (oldest 16) done; G still in flight
#pragma unroll
            for (int i = 0; i < 8; ++i)      // input part (h1): W cols half*256
                acc = MFMA16(*(const short8*)&Wl[wrowb + half * 256 + i * 32 + quad * 8],
                             frag2(F[2 * i], F[2 * i + 1]), acc);
            VMCNT(0);    // G done (overlapped by MFMAs)
#pragma unroll
            for (int i = 0; i < 8; ++i)      // recurrent (h2): W cols 512+half*256
                acc = MFMA16(*(const short8*)&Wl[wrowb + 512 + half * 256 + i * 32 + quad * 8],
                             frag2(G[2 * i], G[2 * i + 1]), acc);
        }
        *(floatx4*)&red[((half * 4 + g) * 16 + c16) * 20 + quad * 4] = acc;
        LGKM0;
        bar();   // B2: C tiles visible in LDS

        // ============== P2: gates + dual h store (waves 0-1) ===================
        if (tid < 128) {
            float hv[2];
#pragma unroll
            for (int jj2 = 0; jj2 < 2; ++jj2) {
                const int jl = 2 * jp + jj2;
                float gv[4];
#pragma unroll
                for (int gg = 0; gg < 4; ++gg)
                    gv[gg] = red[(gg * 16 + bl) * 20 + jl]
                           + red[((4 + gg) * 16 + bl) * 20 + jl] + bias2[jj2][gg];
                const float ig = sigmoidf_fast(gv[0]);
                const float fg = sigmoidf_fast(gv[1]);
                const float gt = tanhf_fast(gv[2]);
                const float og = sigmoidf_fast(gv[3]);
                cst[jj2] = fg * cst[jj2] + ig * gt;
                hv[jj2] = og * tanhf_fast(cst[jj2]);
            }
            const u32 packed = pack2_rne(hv[0], hv[1]);
            if (!isL1) {
                u32* hb32 = (u32*)(h1l_bg + (size_t)(s & 1) * 2048);
                st32_loc(hb32 + hoff, packed, loc);                  // local first
                st32_sc1((u32*)(h1b + (size_t)(s % 3) * HQ) + hsoff, packed);
                VMCNT(1);   // FIFO: local store retired; sc1 feed store in flight
            } else {
                u32* hb32 = (u32*)(h2l_bg + (size_t)(s & 1) * 2048);
                st32_loc(hb32 + hoff, packed, loc);
                VMCNT(0);   // local only (FC reads local) -- cheap L2 drain
            }
        }
        bar();   // B3: h[s] at local coherence point

        // ============== publishes ==============================================
        if (tid == 0) {
            if (!isL1) {
                st32_loc(f0l_bg + rg, (u32)(s + 1), loc);  // h1[s] local-visible
                st32_sc1(f0r_bg + rg, (u32)s);             // h1b[s-1] MALL-visible
            } else {
                st32_loc(f1l_bg + rg, (u32)(s + 1), loc);  // h2[s] local-visible
                st32_sc1(f1r_bg + rg, (u32)(s + 1));       // WAR: consumed h1b[s]
            }
        }
    }

    // ---- L0 post-loop: certify final h1b[Sc-1] for L1's last step ----
    if (!isL1) {
        if (tid < 128) VMCNT(0);     // drain last sc1 h-store (gate waves)
        bar();
        if (tid == 0) st32_sc1(f0r_bg + rg, (u32)Sc);
    }

    // ---- FC epilogue: L1 groups, rg<16 -> batch b = bg*16+rg (h2 is local) ----
    if (isL1 && rg < 16) {
        if (w == 0) {
            int it = 0;
            for (;;) {
                u32 v = ldf_loc(f1l_bg + (lane & 31), loc);
                if (__all(v >= (u32)Sc) || ++it > SPIN1) break;
                __builtin_amdgcn_s_sleep(1);
            }
        }
        __syncthreads();
        const u64* h2f = h2l_bg + (size_t)((Sc - 1) & 1) * 2048;
        const int b = bg * 16 + rg;
        const int o = tid & 127, q = tid >> 7;
        const float* wrow = fcw + (size_t)o * Hc;
        float a = 0.0f;
        for (int k4 = q * 32; k4 < q * 32 + 32; ++k4) {
            const float4 f = unpack4(ld64_sync(h2f + k4 * 16 + rg, loc));
            const float4 wv = *(const float4*)(wrow + 4 * k4);
            a += f.x * wv.x + f.y * wv.y + f.z * wv.z + f.w * wv.w;
        }
        __syncthreads();
        red[q * 128 + o] = a;
        __syncthreads();
        if (tid < OUTc)
            out[b * OUTc + tid] = red[tid] + red[128 + tid] + red[256 + tid]
                                + red[384 + tid] + fcb[tid];
    }
}

extern "C" void kernel_launch(void* const* d_in, const int* in_sizes, int n_in,
                              void* d_out, int out_size, void* d_ws, size_t ws_size,
                              hipStream_t stream) {
    const float* x    = (const float*)d_in[0];
    const float* Wih0 = (const float*)d_in[1];
    const float* Whh0 = (const float*)d_in[2];
    const float* bih0 = (const float*)d_in[3];
    const float* bhh0 = (const float*)d_in[4];
    const float* Wih1 = (const float*)d_in[5];
    const float* Whh1 = (const float*)d_in[6];
    const float* bih1 = (const float*)d_in[7];
    const float* bhh1 = (const float*)d_in[8];
    const float* fcw  = (const float*)d_in[9];
    const float* fcb  = (const float*)d_in[10];
    float* out = (float*)d_out;
    float* wsf = (float*)d_ws;

    hipMemsetAsync(d_ws, 0, WS_BYTES, stream);   // xarr/xdec/flags=0, h[-1]=0

    lstm_persist<<<dim3(NWG), dim3(NTHR), 0, stream>>>(
        x, Wih0, Whh0, bih0, bhh0, Wih1, Whh1, bih1, bhh1, fcw, fcb, out, wsf);
}

// Round 5
// 2572.607 us; speedup vs baseline: 2986.6731x; 2986.6731x over previous
//
#include <hip/hip_runtime.h>

typedef unsigned long long u64;
typedef unsigned int u32;
typedef __attribute__((ext_vector_type(8))) short short8;   // bf16x8 MFMA frag
typedef __attribute__((ext_vector_type(4))) float floatx4;  // f32x4 MFMA acc

// Problem constants
#define Bc   64
#define Sc   512
#define Dc   256
#define Hc   512
#define OUTc 128

// Self-validating-data design (round-4 lesson: only __hip_atomic AGENT ops are
// promptly coherent; sc0 polling reads stale L1 forever).  Every h value is a
// tagged u32 = bf16(h)<<16 | (step+1).  Consumers load the DATA in a retry
// loop and check embedded tags: producer store -> ONE MALL hop -> consumer.
// No flags, no drains, no barriers across WGs on the critical path.
// Intra-layer WAR is self-synchronizing (full-K tag coverage proves all peers
// finished the previous step before any slot is reused).  Only the L0->L1
// feed keeps one lazy WAR flag (slack ~1 step, off critical path).
// 2 loader waves/WG fetch the tagged slice once, strip tags, stage payload in
// padded LDS; all 8 waves read MFMA frags from LDS (4x MALL traffic dedup).
#define NWG  256
#define NTHR 512
#define JPW  16     // j indices per WG
#define NRW  64     // weight rows per WG (4 gates x 16 j)
#define KPB  1032   // bf16 LDS row stride (max K 1024 + 8)
#define SPIN  (1 << 13)   // per-step retry bound (safety valve; ~3ms if hit)
#define SPINF (1 << 16)   // epilogue retry bound

// workspace (memset 0 each launch; tag 0 never matches any step tag >= 1)
#define WAR_OFF  0                   // u32[4 bg][32 rg]: L1 feed-consumed flags
#define H1T_OFF  1024                // u32[2 slot][128 k4][64 b][4]  tagged h1
#define H2T_OFF  (1024 + 262144)     // u32[2 slot][128 k4][64 b][4]  tagged h2
#define WS_BYTES (1024 + 2 * 262144)

__device__ __forceinline__ short bf16_rne(float f) {
    u32 u = __float_as_uint(f);
    u += 0x7fffu + ((u >> 16) & 1u);
    return (short)(u >> 16);
}
__device__ __forceinline__ short8 frag2(u64 a, u64 b) {
    union { u64 u[2]; short8 s; } c; c.u[0] = a; c.u[1] = b; return c.s;
}
__device__ __forceinline__ float sigmoidf_fast(float v) {
    return 1.0f / (1.0f + __expf(-v));
}
__device__ __forceinline__ float tanhf_fast(float v) {
    return 2.0f / (1.0f + __expf(-2.0f * v)) - 1.0f;
}
// proven-prompt coherent primitives (round 0): agent-scope relaxed atomics
__device__ __forceinline__ u64 al64(const u64* p) {
    return __hip_atomic_load(p, __ATOMIC_RELAXED, __HIP_MEMORY_SCOPE_AGENT);
}
__device__ __forceinline__ u32 al32(const u32* p) {
    return __hip_atomic_load(p, __ATOMIC_RELAXED, __HIP_MEMORY_SCOPE_AGENT);
}
__device__ __forceinline__ void as32(u32* p, u32 v) {
    __hip_atomic_store(p, v, __ATOMIC_RELAXED, __HIP_MEMORY_SCOPE_AGENT);
}
#define LGKM0 do { asm volatile("s_waitcnt lgkmcnt(0)" ::: "memory"); } while (0)
__device__ __forceinline__ void bar() {   // raw s_barrier: no implicit drain
    asm volatile("s_barrier" ::: "memory");
}
#define MFMA16(A, B, C) __builtin_amdgcn_mfma_f32_16x16x32_bf16((A), (B), (C), 0, 0, 0)

extern "C" __global__ void __launch_bounds__(NTHR)
lstm_persist(const float* __restrict__ x,
             const float* __restrict__ Wih0, const float* __restrict__ Whh0,
             const float* __restrict__ bih0, const float* __restrict__ bhh0,
             const float* __restrict__ Wih1, const float* __restrict__ Whh1,
             const float* __restrict__ bih1, const float* __restrict__ bhh1,
             const float* __restrict__ fcw, const float* __restrict__ fcb,
             float* __restrict__ out, float* __restrict__ wsf)
{
    __shared__ short Wl[NRW * KPB];          // 129 KB bf16 weights, resident
    __shared__ float red[8 * 16 * 20];       // 10 KB C-park / FC reduce
    __shared__ u64 hshare[128 * 17];         // 17 KB padded payload stage

    char* wsb = (char*)wsf;
    u32* war = (u32*)(wsb + WAR_OFF);
    u64* h1t = (u64*)(wsb + H1T_OFF);        // [slot][k4*64+b] pairs of u64
    u64* h2t = (u64*)(wsb + H2T_OFF);

    const int wg  = blockIdx.x;
    const int tid = threadIdx.x;
    const bool isL1 = wg >= 128;
    const int wgl = isL1 ? wg - 128 : wg;
    const int rg = wgl >> 2, bg = wgl & 3;
    const int j0 = rg * JPW;
    const int K  = isL1 ? 1024 : 768;
    const int KD = isL1 ? 512  : 256;

    // ---- one-time weight staging: 64 rows (g*16+jl) x K, fp32 -> bf16 ----
    {
        const float* Wi = isL1 ? Wih1 : Wih0;
        const float* Wh = isL1 ? Whh1 : Whh0;
        for (int r = 0; r < NRW; ++r) {
            const int row = (r >> 4) * Hc + j0 + (r & 15);
            for (int c = tid; c < K; c += NTHR) {
                float v = (c < KD) ? Wi[(size_t)row * KD + c] : Wh[(size_t)row * Hc + (c - KD)];
                Wl[r * KPB + c] = bf16_rne(v);
            }
        }
    }
    __syncthreads();

    // MFMA wave mapping (proven): w = (gate g)*2 + K-half
    const int w = tid >> 6, lane = tid & 63;
    const int g = w >> 1, half = w & 1;
    const int quad = lane >> 4, c16 = lane & 15;
    const int bglob = bg * 16 + c16;
    const int wrowb = (g * 16 + c16) * KPB;
    // loader mapping: waves g==0 load slice A, g==1 slice B (L1 h2); per lane
    // 16 blocks k4 = half*64 + quad*16 + r, b = bglob
    const size_t lofs = ((size_t)(half * 64 + quad * 16) * 64 + bglob) * 2;

    // cell mapping: tid<128 -> (bl, jp), 2 cells (j = j0+2jp, +1)
    const int bl = tid & 15, jp = tid >> 4;
    float cst[2] = {0.0f, 0.0f};
    float bias2[2][4];
    {
        const float* bi = isL1 ? bih1 : bih0;
        const float* bh = isL1 ? bhh1 : bhh0;
#pragma unroll
        for (int jj2 = 0; jj2 < 2; ++jj2) {
            const int j = j0 + 2 * jp + jj2;
#pragma unroll
            for (int gg = 0; gg < 4; ++gg)
                bias2[jj2][gg] = bi[gg * Hc + j] + bh[gg * Hc + j];
        }
    }
    // gate store offset (u64 units within a slot): [k4][b] pair + (jp&1)
    const size_t gofs = ((size_t)(rg * 4 + (jp >> 1)) * 64 + bg * 16 + bl) * 2 + (jp & 1);

    u32 warv = 0;   // w0 lanes: cached L1 feed-consumed flags

    for (int s = 0; s < Sc; ++s) {
        floatx4 acc = {0.0f, 0.0f, 0.0f, 0.0f};
        u64 T2[32];

        if (!isL1) {
            // ---- x-phase: dependency-free, overlaps producers' store latency ----
            {
                const float* xp = x + (size_t)bglob * Sc * Dc + (size_t)s * Dc
                                + half * 128 + quad * 8;
                float Xv[32];
#pragma unroll
                for (int i = 0; i < 8; ++i)
                    *(float4*)&Xv[4 * i] = *(const float4*)(xp + (i >> 1) * 32 + (i & 1) * 4);
#pragma unroll
                for (int i = 0; i < 4; ++i) {
                    short8 Bv;
#pragma unroll
                    for (int jj = 0; jj < 8; ++jj) Bv[jj] = bf16_rne(Xv[i * 8 + jj]);
                    acc = MFMA16(*(const short8*)&Wl[wrowb + half * 128 + i * 32 + quad * 8], Bv, acc);
                }
            }
            // ---- loaders (waves 0,1): tag-retry h1[s-1], stage payload in LDS ----
            if (g == 0 && s > 0) {
                const u64* src = h1t + (size_t)((s + 1) & 1) * 16384 + lofs;
                const u32 want = (u32)s & 0xffffu;
                for (int it = 0;; ++it) {
#pragma unroll
                    for (int r = 0; r < 16; ++r) {
                        T2[2 * r]     = al64(src + (size_t)r * 128);
                        T2[2 * r + 1] = al64(src + (size_t)r * 128 + 1);
                    }
                    u32 bad = 0;
#pragma unroll
                    for (int r = 0; r < 32; ++r)
                        bad |= ((u32)T2[r] ^ want) | ((u32)(T2[r] >> 32) ^ want);
                    if (__all((bad & 0xffffu) == 0) || it > SPIN) break;
                }
#pragma unroll
                for (int r = 0; r < 16; ++r) {
                    u32 p0 = ((u32)T2[2 * r] >> 16)     | ((u32)(T2[2 * r] >> 32) & 0xffff0000u);
                    u32 p1 = ((u32)T2[2 * r + 1] >> 16) | ((u32)(T2[2 * r + 1] >> 32) & 0xffff0000u);
                    hshare[(half * 64 + quad * 16 + r) * 17 + c16] = ((u64)p1 << 32) | p0;
                }
                LGKM0;
            }
            // ---- lazy cross-layer WAR: gates-s clobbers h1[s-2]; need L1 fed s-2 ----
            if (w == 0 && s >= 2) {
                const u32 need = (u32)(s - 1);
                if (!__all(warv >= need)) {
                    int it = 0;
                    do { warv = al32(war + bg * 32 + (lane & 31)); }
                    while (!__all(warv >= need) && ++it < SPIN);
                }
            }
            bar();   // B_ds: payload staged
            if (s > 0) {
#pragma unroll
                for (int i = 0; i < 8; ++i) {
                    const int q8 = half * 64 + i * 8 + quad * 2;
                    u64 d0 = hshare[q8 * 17 + c16];
                    u64 d1 = hshare[(q8 + 1) * 17 + c16];
                    acc = MFMA16(*(const short8*)&Wl[wrowb + 256 + half * 256 + i * 32 + quad * 8],
                                 frag2(d0, d1), acc);
                }
            }
        } else {
            // ---- h2 loaders (waves 2,3): issue loads now, validate after B_mid ----
            if (g == 1 && s > 0) {
                const u64* src = h2t + (size_t)((s + 1) & 1) * 16384 + lofs;
#pragma unroll
                for (int r = 0; r < 16; ++r) {
                    T2[2 * r]     = al64(src + (size_t)r * 128);
                    T2[2 * r + 1] = al64(src + (size_t)r * 128 + 1);
                }
            }
            // ---- feed loaders (waves 0,1): tag-retry h1[s], stage payload ----
            if (g == 0) {
                const u64* src = h1t + (size_t)(s & 1) * 16384 + lofs;
                const u32 want = (u32)(s + 1) & 0xffffu;
                u64 T[32];
                for (int it = 0;; ++it) {
#pragma unroll
                    for (int r = 0; r < 16; ++r) {
                        T[2 * r]     = al64(src + (size_t)r * 128);
                        T[2 * r + 1] = al64(src + (size_t)r * 128 + 1);
                    }
                    u32 bad = 0;
#pragma unroll
                    for (int r = 0; r < 32; ++r)
                        bad |= ((u32)T[r] ^ want) | ((u32)(T[r] >> 32) ^ want);
                    if (__all((bad & 0xffffu) == 0) || it > SPIN) break;
                }
#pragma unroll
                for (int r = 0; r < 16; ++r) {
                    u32 p0 = ((u32)T[2 * r] >> 16)     | ((u32)(T[2 * r] >> 32) & 0xffff0000u);
                    u32 p1 = ((u32)T[2 * r + 1] >> 16) | ((u32)(T[2 * r + 1] >> 32) & 0xffff0000u);
                    hshare[(half * 64 + quad * 16 + r) * 17 + c16] = ((u64)p1 << 32) | p0;
                }
                LGKM0;
            }
            bar();   // B_ds: feed staged
            if (tid == 256) as32(war + bg * 32 + rg, (u32)(s + 1));   // feed consumed
            // input part (h1): W cols half*256
#pragma unroll
            for (int i = 0; i < 8; ++i) {
                const int q8 = half * 64 + i * 8 + quad * 2;
                u64 d0 = hshare[q8 * 17 + c16];
                u64 d1 = hshare[(q8 + 1) * 17 + c16];
                acc = MFMA16(*(const short8*)&Wl[wrowb + half * 256 + i * 32 + quad * 8],
                             frag2(d0, d1), acc);
            }
            LGKM0;
            bar();   // B_mid: hshare free for h2 payload
            if (g == 1 && s > 0) {
                const u64* src = h2t + (size_t)((s + 1) & 1) * 16384 + lofs;
                const u32 want = (u32)s & 0xffffu;
                for (int it = 0;; ++it) {
                    u32 bad = 0;
#pragma unroll
                    for (int r = 0; r < 32; ++r)
                        bad |= ((u32)T2[r] ^ want) | ((u32)(T2[r] >> 32) ^ want);
                    if (__all((bad & 0xffffu) == 0) || it > SPIN) break;
#pragma unroll
                    for (int r = 0; r < 16; ++r) {
                        T2[2 * r]     = al64(src + (size_t)r * 128);
                        T2[2 * r + 1] = al64(src + (size_t)r * 128 + 1);
                    }
                }
#pragma unroll
                for (int r = 0; r < 16; ++r) {
                    u32 p0 = ((u32)T2[2 * r] >> 16)     | ((u32)(T2[2 * r] >> 32) & 0xffff0000u);
                    u32 p1 = ((u32)T2[2 * r + 1] >> 16) | ((u32)(T2[2 * r + 1] >> 32) & 0xffff0000u);
                    hshare[(half * 64 + quad * 16 + r) * 17 + c16] = ((u64)p1 << 32) | p0;
                }
                LGKM0;
            }
            bar();   // B_mid2: h2 payload staged
            if (s > 0) {
#pragma unroll
                for (int i = 0; i < 8; ++i) {   // recurrent (h2): W cols 512+half*256
                    const int q8 = half * 64 + i * 8 + quad * 2;
                    u64 d0 = hshare[q8 * 17 + c16];
                    u64 d1 = hshare[(q8 + 1) * 17 + c16];
                    acc = MFMA16(*(const short8*)&Wl[wrowb + 512 + half * 256 + i * 32 + quad * 8],
                                 frag2(d0, d1), acc);
                }
            }
        }

        // ---- park C tile ----
        *(floatx4*)&red[((half * 4 + g) * 16 + c16) * 20 + quad * 4] = acc;
        LGKM0;
        bar();   // B2

        // ---- gates + tagged h store (fire-and-forget; tags self-certify) ----
        if (tid < 128) {
            float hv[2];
#pragma unroll
            for (int jj2 = 0; jj2 < 2; ++jj2) {
                const int jl = 2 * jp + jj2;
                float gv[4];
#pragma unroll
                for (int gg = 0; gg < 4; ++gg)
                    gv[gg] = red[(gg * 16 + bl) * 20 + jl]
                           + red[((4 + gg) * 16 + bl) * 20 + jl] + bias2[jj2][gg];
                const float ig = sigmoidf_fast(gv[0]);
                const float fg = sigmoidf_fast(gv[1]);
                const float gt = tanhf_fast(gv[2]);
                const float og = sigmoidf_fast(gv[3]);
                cst[jj2] = fg * cst[jj2] + ig * gt;
                hv[jj2] = og * tanhf_fast(cst[jj2]);
            }
            const u32 tg = (u32)(s + 1) & 0xffffu;
            const u32 lo = tg | ((u32)(unsigned short)bf16_rne(hv[0]) << 16);
            const u32 hi = tg | ((u32)(unsigned short)bf16_rne(hv[1]) << 16);
            u32* dst = (u32*)((isL1 ? h2t : h1t) + (size_t)(s & 1) * 16384 + gofs);
            as32(dst, lo);
            as32(dst + 1, hi);
        }
        bar();   // B3
    }

    // ---- FC epilogue: WG b in [0,64) (L0 WGs, free first); tag-retry h2[Sc-1] ----
    if (wg < Bc) {
        __syncthreads();
        const int b = wg;
        const u64* h2f = h2t + (size_t)((Sc - 1) & 1) * 16384;
        const u32 want = (u32)Sc & 0xffffu;
        const int o = tid & 127, q = tid >> 7;
        const float* wrow = fcw + (size_t)o * Hc;
        float a = 0.0f;
        for (int k4 = q * 32; k4 < q * 32 + 32; ++k4) {
            const u64* p = h2f + ((size_t)k4 * 64 + b) * 2;
            u64 t0, t1; int it = 0;
            for (;;) {
                t0 = al64(p); t1 = al64(p + 1);
                u32 bad = (((u32)t0 ^ want) | ((u32)(t0 >> 32) ^ want)
                         | ((u32)t1 ^ want) | ((u32)(t1 >> 32) ^ want)) & 0xffffu;
                if (bad == 0 || ++it > SPINF) break;
            }
            const float* wr = wrow + 4 * k4;
            a += __uint_as_float((u32)t0 & 0xffff0000u)         * wr[0]
               + __uint_as_float((u32)(t0 >> 32) & 0xffff0000u) * wr[1]
               + __uint_as_float((u32)t1 & 0xffff0000u)         * wr[2]
               + __uint_as_float((u32)(t1 >> 32) & 0xffff0000u) * wr[3];
        }
        __syncthreads();
        red[q * 128 + o] = a;
        __syncthreads();
        if (tid < OUTc)
            out[b * OUTc + tid] = red[tid] + red[128 + tid] + red[256 + tid]
                                + red[384 + tid] + fcb[tid];
    }
}

extern "C" void kernel_launch(void* const* d_in, const int* in_sizes, int n_in,
                              void* d_out, int out_size, void* d_ws, size_t ws_size,
                              hipStream_t stream) {
    const float* x    = (const float*)d_in[0];
    const float* Wih0 = (const float*)d_in[1];
    const float* Whh0 = (const float*)d_in[2];
    const float* bih0 = (const float*)d_in[3];
    const float* bhh0 = (const float*)d_in[4];
    const float* Wih1 = (const float*)d_in[5];
    const float* Whh1 = (const float*)d_in[6];
    const float* bih1 = (const float*)d_in[7];
    const float* bhh1 = (const float*)d_in[8];
    const float* fcw  = (const float*)d_in[9];
    const float* fcb  = (const float*)d_in[10];
    float* out = (float*)d_out;
    float* wsf = (float*)d_ws;

    hipMemsetAsync(d_ws, 0, WS_BYTES, stream);   // tags=0 (< any step tag), war=0

    lstm_persist<<<dim3(NWG), dim3(NTHR), 0, stream>>>(
        x, Wih0, Whh0, bih0, bhh0, Wih1, Whh1, bih1, bhh1, fcw, fcb, out, wsf);
}